// Round 4
// baseline (352.034 us; speedup 1.0000x reference)
//
#include <hip/hip_runtime.h>

// HemorrhageNet: per-row Poisson-binomial count distribution over 96 probs,
// truncated/saturated at 5, binned to severity[5] = {c0, c1+c2, c3+c4, c5, 0}.
//
// R4: R3's math (4 lanes/row, 24 probs/lane, 2-level butterfly, mass
// conservation for c5 — absmax ~1e-29 validated) plus latency-hiding
// structure the compiler can't defeat:
//  - each thread processes ITERS=4 row-tiles, software-pipelined: tile i+1's
//    6 float4 loads are issued BEFORE tile i's compute;
//  - __builtin_amdgcn_sched_barrier(0) after each prefetch block pins the
//    loads above the compute (R2/R3 evidence: VGPR_Count=16/20 -> compiler
//    sank loads into dependent serial round trips; MLP was the limiter);
//  - 4x fewer waves (16K vs 65K) amortizes wave launch/drain dead time.

#define THREADS 256
#define LPR 4                          // lanes per row
#define RPI (THREADS / LPR)            // 64 rows per iteration
#define ITERS 4
#define ROWS_PER_BLOCK (RPI * ITERS)   // 256 rows per block

__global__ __launch_bounds__(THREADS, 6) void hemorrhage_kernel(
    const float* __restrict__ x1,
    const float* __restrict__ x2,
    const float* __restrict__ x3,
    float* __restrict__ out)
{
    const int t = threadIdx.x;
    const int q4 = t & 3;                       // quarter-row slot
    const int rg = t >> 2;                      // row within tile
    const uint32_t row0 = (uint32_t)blockIdx.x * ROWS_PER_BLOCK + rg;

    // 32-bit offsets (max 32M floats) -> SGPR-base + VGPR-offset addressing
    uint32_t foff = row0 * 32u + (uint32_t)q4 * 8u;
    const uint32_t fstride = RPI * 32u;

    float4 cur0, cur1, cur2, cur3, cur4, cur5;
    cur0 = *(const float4*)(x1 + foff);
    cur1 = *(const float4*)(x1 + foff + 4);
    cur2 = *(const float4*)(x2 + foff);
    cur3 = *(const float4*)(x2 + foff + 4);
    cur4 = *(const float4*)(x3 + foff);
    cur5 = *(const float4*)(x3 + foff + 4);

#pragma unroll
    for (int it = 0; it < ITERS; ++it) {
        // ---- prefetch next tile (6 independent 16B loads) ----
        float4 nxt0, nxt1, nxt2, nxt3, nxt4, nxt5;
        const uint32_t nf = foff + fstride;
        if (it + 1 < ITERS) {
            nxt0 = *(const float4*)(x1 + nf);
            nxt1 = *(const float4*)(x1 + nf + 4);
            nxt2 = *(const float4*)(x2 + nf);
            nxt3 = *(const float4*)(x2 + nf + 4);
            nxt4 = *(const float4*)(x3 + nf);
            nxt5 = *(const float4*)(x3 + nf + 4);
        }
        // pin: prefetch loads may not sink below, compute may not hoist above
        __builtin_amdgcn_sched_barrier(0);

        // ---- truncated distribution over this lane's 24 probs ----
        float a0 = 1.0f, a1 = 0.0f, a2 = 0.0f, a3 = 0.0f, a4 = 0.0f;

#define STEP(P)                          \
    do {                                 \
        const float p_ = (P);            \
        const float q_ = 1.0f - p_;      \
        a4 = fmaf(a4, q_, a3 * p_);      \
        a3 = fmaf(a3, q_, a2 * p_);      \
        a2 = fmaf(a2, q_, a1 * p_);      \
        a1 = fmaf(a1, q_, a0 * p_);      \
        a0 = a0 * q_;                    \
    } while (0)

        STEP(cur0.x); STEP(cur0.y); STEP(cur0.z); STEP(cur0.w);
        STEP(cur1.x); STEP(cur1.y); STEP(cur1.z); STEP(cur1.w);
        STEP(cur2.x); STEP(cur2.y); STEP(cur2.z); STEP(cur2.w);
        STEP(cur3.x); STEP(cur3.y); STEP(cur3.z); STEP(cur3.w);
        STEP(cur4.x); STEP(cur4.y); STEP(cur4.z); STEP(cur4.w);
        STEP(cur5.x); STEP(cur5.y); STEP(cur5.z); STEP(cur5.w);
#undef STEP

        // ---- 2-level butterfly combine across the 4-lane group ----
#pragma unroll
        for (int d = 1; d < LPR; d <<= 1) {
            const float b0 = __shfl_xor(a0, d);
            const float b1 = __shfl_xor(a1, d);
            const float b2 = __shfl_xor(a2, d);
            const float b3 = __shfl_xor(a3, d);
            const float b4 = __shfl_xor(a4, d);

            float n0 = a0 * b0;
            float n1 = a0 * b1;
            n1 = fmaf(a1, b0, n1);
            float n2 = a0 * b2;
            n2 = fmaf(a1, b1, n2);
            n2 = fmaf(a2, b0, n2);
            float n3 = a0 * b3;
            n3 = fmaf(a1, b2, n3);
            n3 = fmaf(a2, b1, n3);
            n3 = fmaf(a3, b0, n3);
            float n4 = a0 * b4;
            n4 = fmaf(a1, b3, n4);
            n4 = fmaf(a2, b2, n4);
            n4 = fmaf(a3, b1, n4);
            n4 = fmaf(a4, b0, n4);

            a0 = n0; a1 = n1; a2 = n2; a3 = n3; a4 = n4;
        }

        // ---- severity; c5 via mass conservation ----
        const float sev0 = a0;
        const float sev1 = a1 + a2;
        const float sev2 = a3 + a4;
        const float sev3 = 1.0f - (sev0 + sev1 + sev2);   // = c5

        float vstore = sev3;
        if (q4 == 0) vstore = sev0;
        else if (q4 == 1) vstore = sev1;
        else if (q4 == 2) vstore = sev2;

        float* orow = out + (size_t)(row0 + (uint32_t)it * RPI) * 5;
        orow[q4] = vstore;
        if (q4 == 0) orow[4] = 0.0f;   // out re-poisoned 0xAA: write zero col

        // ---- rotate buffers ----
        cur0 = nxt0; cur1 = nxt1; cur2 = nxt2;
        cur3 = nxt3; cur4 = nxt4; cur5 = nxt5;
        foff = nf;
    }
}

extern "C" void kernel_launch(void* const* d_in, const int* in_sizes, int n_in,
                              void* d_out, int out_size, void* d_ws, size_t ws_size,
                              hipStream_t stream) {
    const float* x1 = (const float*)d_in[0];
    const float* x2 = (const float*)d_in[1];
    const float* x3 = (const float*)d_in[2];
    float* out = (float*)d_out;

    const int rows = in_sizes[0] / 32;             // 1048576
    const int blocks = rows / ROWS_PER_BLOCK;      // 4096 (exact)
    hemorrhage_kernel<<<blocks, THREADS, 0, stream>>>(x1, x2, x3, out);
}